// Round 8
// baseline (487.655 us; speedup 1.0000x reference)
//
#include <hip/hip_runtime.h>
#include <hip/hip_bf16.h>

// ---------------------------------------------------------------------------
// GAT 2-layer model on MI355X — round 16.
// R15 post-mortem: tail vectorization null. Counter insight: acc[8][4] lives
// in AGPRs -> true reg use ~236/wave -> all R10-R14 GEMMs ran 1 block/CU
// (zero cross-block TLP; the m97 ~37% mechanism needs ~2-3 blocks/CU).
// R16: 256x128 tile, 8 waves, acc[4][4] (64 AGPR + ~60 VGPR), ring-2 x 24KB
// LDS (48KB total) -> 2 blocks/CU. Simple vmcnt(0)+1-barrier step (m97
// structure), stage-ahead-1, setprio MFMA cluster. l1: 1536 blocks (3 even
// rounds @2/CU); l2: KSPLIT=4, 768 blocks. l1 epilogue: 64-row quarter
// transposes (fits 48KB). prep_aw fused into W1 frag_transpose (atomics).
// Layer1 commuted: z = softmax-agg of x rows; h2 = ELU(z_h @ W1_h + b1).
// Layer2: y = h2@W2 split-K=4 -> fused reduce+alpha -> attn2+b2.
// ---------------------------------------------------------------------------

#define N_NODES 8192
#define N_EDGES 32768
#define E_TOT   (N_EDGES + N_NODES)   // self-loops appended
#define D_IN    768
#define H1      8
#define HC1     (H1 * D_IN)           // 6144
#define KSPLIT  4
#define KSLICE  (HC1 / KSPLIT)        // 1536

typedef unsigned short ushort_t;
using short8  = __attribute__((ext_vector_type(8))) short;
using short4v = __attribute__((ext_vector_type(4))) short;
using floatx4 = __attribute__((ext_vector_type(4))) float;

__device__ __forceinline__ float bf2f(unsigned short u) {
  return __uint_as_float(((unsigned)u) << 16);
}
__device__ __forceinline__ unsigned short f2bf(float f) {
  unsigned u = __float_as_uint(f);
  unsigned r = (u + 0x7fffu + ((u >> 16) & 1u)) >> 16;  // RNE
  return (unsigned short)r;
}

// async global->LDS: 16B per lane, wave-uniform LDS base (+lane*16 implicit),
// per-lane global src address.
__device__ __forceinline__ void gll16(const ushort_t* g, ushort_t* l) {
  __builtin_amdgcn_global_load_lds(
      (const __attribute__((address_space(1))) void*)g,
      (__attribute__((address_space(3))) void*)l, 16, 0, 0);
}

// ---------------------------------------------------------------------------
// frag_transpose (generic, W2): W[Kdim][Ndim] fp32 -> sw-layout Bt[N][K] bf16.
// 64x64 tile via padded LDS; coalesced 256-B row reads.
// ---------------------------------------------------------------------------
__global__ __launch_bounds__(256) void frag_transpose_kernel(
    const float* __restrict__ W, ushort_t* __restrict__ out,
    int Kdim, int Ndim) {
  __shared__ float lds[64 * 65];
  const int bx = blockIdx.x;           // n-tile (64 cols)
  const int by = blockIdx.y;           // k-tile (64 rows)
  const int tid = threadIdx.x;
  const int n0 = bx * 64, k0 = by * 64;
  const int nn = tid & 63, kq = tid >> 6;   // 4 rows per iter
#pragma unroll
  for (int it = 0; it < 16; ++it) {
    int kk = it * 4 + kq;
    lds[kk * 65 + nn] = W[(size_t)(k0 + kk) * Ndim + n0 + nn];
  }
  __syncthreads();
  const int Ksub = Kdim >> 5;
#pragma unroll
  for (int it = 0; it < 2; ++it) {
    int idx = tid + 256 * it;          // 0..511: 8 chunks x 64 lanes
    int c = idx >> 6, l = idx & 63;
    int cn = c >> 1, ck = c & 1;
    int lrow = l & 15, lq = l >> 4;
    int n_loc = cn * 16 + lrow;
    int kb = ck * 32 + lq * 8;
    ushort_t v[8];
#pragma unroll
    for (int e = 0; e < 8; ++e) v[e] = f2bf(lds[(kb + e) * 65 + n_loc]);
    size_t chunk = (size_t)(bx * 4 + cn) * Ksub + (by * 2 + ck);
    *(short8*)(out + chunk * 512 + l * 8) = *(short8*)v;
  }
}

// ---------------------------------------------------------------------------
// fused W1 transpose + aw dots (R16): same transpose as above (Kdim=768,
// Ndim=6144) PLUS per-tile partial awS/awD dots accumulated via atomics.
// awS[d*H1+h] = sum_c W1[d][h*768+c]*aS[h*768+c]. Requires awS/awD zeroed.
// ---------------------------------------------------------------------------
__global__ __launch_bounds__(256) void frag_transpose_aw_kernel(
    const float* __restrict__ W, ushort_t* __restrict__ out,
    const float* __restrict__ aS, const float* __restrict__ aD,
    float* __restrict__ awS, float* __restrict__ awD) {
  __shared__ float lds[64 * 65];
  const int bx = blockIdx.x;           // n-tile (64 of 6144)
  const int by = blockIdx.y;           // k-tile (64 of 768)
  const int tid = threadIdx.x;
  const int n0 = bx * 64, k0 = by * 64;
  const int nn = tid & 63, kq = tid >> 6;
#pragma unroll
  for (int it = 0; it < 16; ++it) {
    int kk = it * 4 + kq;
    lds[kk * 65 + nn] = W[(size_t)(k0 + kk) * 6144 + n0 + nn];
  }
  __syncthreads();
  // transpose output (Ksub = 24)
#pragma unroll
  for (int it = 0; it < 2; ++it) {
    int idx = tid + 256 * it;
    int c = idx >> 6, l = idx & 63;
    int cn = c >> 1, ck = c & 1;
    int lrow = l & 15, lq = l >> 4;
    int n_loc = cn * 16 + lrow;
    int kb = ck * 32 + lq * 8;
    ushort_t v[8];
#pragma unroll
    for (int e = 0; e < 8; ++e) v[e] = f2bf(lds[(kb + e) * 65 + n_loc]);
    size_t chunk = (size_t)(bx * 4 + cn) * 24 + (by * 2 + ck);
    *(short8*)(out + chunk * 512 + l * 8) = *(short8*)v;
  }
  // aw partial dots: row r = tid>>2, col quarter nq = tid&3
  const int r = tid >> 2, nq = tid & 3;
  float s_ = 0.f, d_ = 0.f;
  const float* aSp = aS + n0 + nq * 16;
  const float* aDp = aD + n0 + nq * 16;
#pragma unroll
  for (int c = 0; c < 16; ++c) {
    float v = lds[r * 65 + nq * 16 + c];
    s_ += v * aSp[c];
    d_ += v * aDp[c];
  }
  s_ += __shfl_down(s_, 2, 4); s_ += __shfl_down(s_, 1, 4);
  d_ += __shfl_down(d_, 2, 4); d_ += __shfl_down(d_, 1, 4);
  if (nq == 0) {
    int h = n0 / 768;
    atomicAdd(&awS[(k0 + r) * H1 + h], s_);
    atomicAdd(&awD[(k0 + r) * H1 + h], d_);
  }
}

// ---------------------------------------------------------------------------
// per node: xb = bf16(x); as1[n,h] = x[n,:]@awS[:,h]; ad1 likewise.
// ---------------------------------------------------------------------------
__global__ void node_prep_kernel(const float* __restrict__ x,
                                 const float* __restrict__ awS,
                                 const float* __restrict__ awD,
                                 ushort_t* __restrict__ xb,
                                 float* __restrict__ as1,
                                 float* __restrict__ ad1) {
  const int n = blockIdx.x;
  const int t = threadIdx.x;
  float ps[H1], pd[H1];
#pragma unroll
  for (int h = 0; h < H1; ++h) { ps[h] = 0.f; pd[h] = 0.f; }
#pragma unroll
  for (int j = 0; j < 3; ++j) {
    int d = j * 256 + t;
    float xv = x[(size_t)n * 768 + d];
    xb[(size_t)n * 768 + d] = f2bf(xv);
    const float4* s4 = (const float4*)(awS + d * 8);
    const float4* d4 = (const float4*)(awD + d * 8);
    float4 a0 = s4[0], a1 = s4[1];
    float4 c0 = d4[0], c1 = d4[1];
    ps[0] += xv * a0.x; ps[1] += xv * a0.y; ps[2] += xv * a0.z; ps[3] += xv * a0.w;
    ps[4] += xv * a1.x; ps[5] += xv * a1.y; ps[6] += xv * a1.z; ps[7] += xv * a1.w;
    pd[0] += xv * c0.x; pd[1] += xv * c0.y; pd[2] += xv * c0.z; pd[3] += xv * c0.w;
    pd[4] += xv * c1.x; pd[5] += xv * c1.y; pd[6] += xv * c1.z; pd[7] += xv * c1.w;
  }
#pragma unroll
  for (int h = 0; h < H1; ++h)
    for (int off = 32; off > 0; off >>= 1) {
      ps[h] += __shfl_down(ps[h], off, 64);
      pd[h] += __shfl_down(pd[h], off, 64);
    }
  __shared__ float red[2][4][H1];
  int w = t >> 6;
  if ((t & 63) == 0) {
#pragma unroll
    for (int h = 0; h < H1; ++h) { red[0][w][h] = ps[h]; red[1][w][h] = pd[h]; }
  }
  __syncthreads();
  if (t < H1)
    as1[n * H1 + t] = red[0][0][t] + red[0][1][t] + red[0][2][t] + red[0][3][t];
  else if (t >= 64 && t < 64 + H1) {
    int h = t - 64;
    ad1[n * H1 + h] = red[1][0][h] + red[1][1][h] + red[1][2][h] + red[1][3][h];
  }
}

// ---------------------------------------------------------------------------
// CSR build: deg -> exclusive scan -> fill
// ---------------------------------------------------------------------------
__global__ void deg_kernel(const int* __restrict__ dst, int* __restrict__ deg) {
  int e = blockIdx.x * blockDim.x + threadIdx.x;
  if (e >= E_TOT) return;
  int d = (e < N_EDGES) ? dst[e] : (e - N_EDGES);
  atomicAdd(&deg[d], 1);
}

__global__ void scan_kernel(const int* __restrict__ deg, int* __restrict__ start,
                            int* __restrict__ cursor) {
  __shared__ int sums[1024];
  int t = threadIdx.x;
  int base = t * 8;
  int local[8];
  int s = 0;
#pragma unroll
  for (int i = 0; i < 8; ++i) { local[i] = s; s += deg[base + i]; }
  sums[t] = s;
  __syncthreads();
  for (int off = 1; off < 1024; off <<= 1) {
    int v = (t >= off) ? sums[t - off] : 0;
    __syncthreads();
    sums[t] += v;
    __syncthreads();
  }
  int excl = (t == 0) ? 0 : sums[t - 1];
#pragma unroll
  for (int i = 0; i < 8; ++i) {
    int st = excl + local[i];
    start[base + i] = st;
    cursor[base + i] = st;
  }
}

__global__ void fill_kernel(const int* __restrict__ dst, int* __restrict__ cursor,
                            int* __restrict__ csr) {
  int e = blockIdx.x * blockDim.x + threadIdx.x;
  if (e >= E_TOT) return;
  int d = (e < N_EDGES) ? dst[e] : (e - N_EDGES);
  int pos = atomicAdd(&cursor[d], 1);
  csr[pos] = e;
}

// ---------------------------------------------------------------------------
// Fused layer-1 attention -> z in sw (fragment-tiled) layout. (R13)
// ---------------------------------------------------------------------------
__global__ __launch_bounds__(256) void attn1_kernel(
    const ushort_t* __restrict__ xb, const float* __restrict__ as1,
    const float* __restrict__ ad1, const int* __restrict__ start,
    const int* __restrict__ deg, const int* __restrict__ csr,
    const int* __restrict__ src, ushort_t* __restrict__ z_sw) {
  const int n = blockIdx.x;
  const int t = threadIdx.x;
  const int st = start[n], dg = deg[n];
  const int h = t & 7, eloc = t >> 3;  // phase A: 32 edges x 8 heads
  __shared__ float invd[H1];
  __shared__ float alphaS[16][H1];
  __shared__ int sidx[16];
  __shared__ float red[4][H1];
  __shared__ uint4 xs[16 * 96];        // 24 KB: 16 rows x 768 bf16

  // Phase A: denominators (no max-subtraction; logits bounded)
  const float adv = ad1[n * H1 + h];
  float pden = 0.f;
  for (int base = 0; base < dg; base += 32) {
    int ei = base + eloc;
    if (ei < dg) {
      int e = csr[st + ei];
      int s = (e < N_EDGES) ? src[e] : (e - N_EDGES);
      float l = as1[s * H1 + h] + adv;
      l = l > 0.f ? l : 0.2f * l;
      pden += __expf(l);
    }
  }
  pden += __shfl_down(pden, 8, 64);
  pden += __shfl_down(pden, 16, 64);
  pden += __shfl_down(pden, 32, 64);
  if ((t & 63) < 8) red[t >> 6][h] = pden;
  __syncthreads();
  if (t < 8) invd[t] = 1.0f / (red[0][t] + red[1][t] + red[2][t] + red[3][t]);
  __syncthreads();

  // per-pass ownership
  int hp[3], ip[3];
#pragma unroll
  for (int p = 0; p < 3; ++p) {
    int c8 = p * 256 + t;
    hp[p] = c8 / 96;          // head
    ip[p] = c8 % 96;          // uint4 index within a row
  }
  float acc[3][8];
#pragma unroll
  for (int p = 0; p < 3; ++p)
#pragma unroll
    for (int e = 0; e < 8; ++e) acc[p][e] = 0.f;

  for (int base = 0; base < dg; base += 16) {
    int cnt = dg - base; if (cnt > 16) cnt = 16;
    if (t < 128 && eloc < cnt) {
      int e = csr[st + base + eloc];
      int s = (e < N_EDGES) ? src[e] : (e - N_EDGES);
      float l = as1[s * H1 + h] + adv;
      l = l > 0.f ? l : 0.2f * l;
      alphaS[eloc][h] = __expf(l) * invd[h];
      if (h == 0) sidx[eloc] = s;
    }
    __syncthreads();
#pragma unroll
    for (int j = 0; j < 6; ++j) {
      int idx = t + 256 * j;           // 0..1535
      int row = idx / 96;
      if (row < cnt) {
        int col = idx - row * 96;
        xs[idx] = *(const uint4*)(xb + (size_t)sidx[row] * 768 + col * 8);
      }
    }
    __syncthreads();
    for (int ei = 0; ei < cnt; ++ei) {
      const uint4* xr = &xs[ei * 96];
#pragma unroll
      for (int p = 0; p < 3; ++p) {
        uint4 v = xr[ip[p]];
        float al = alphaS[ei][hp[p]];
        unsigned uu[4] = {v.x, v.y, v.z, v.w};
#pragma unroll
        for (int q = 0; q < 4; ++q) {
          acc[p][2 * q]     += al * __uint_as_float(uu[q] << 16);
          acc[p][2 * q + 1] += al * __uint_as_float(uu[q] & 0xffff0000u);
        }
      }
    }
    __syncthreads();
  }
  // write sw layout: k = (p*256+t)*8
#pragma unroll
  for (int p = 0; p < 3; ++p) {
    int c8 = p * 256 + t;
    int k = c8 * 8;
    size_t chunk = (size_t)(n >> 4) * 192 + (k >> 5);
    int word = ((k >> 3) & 3) * 16 + (n & 15);
    ushort_t v[8];
#pragma unroll
    for (int e = 0; e < 8; ++e) v[e] = f2bf(acc[p][e]);
    *(short8*)(z_sw + chunk * 512 + word * 8) = *(short8*)v;
  }
}

// ---------------------------------------------------------------------------
// R16 GEMM: 256x128 tile, 8 waves (wm=w>>1 in 0..3: 64 rows; wn=w&1: 64 cols),
// acc[4][4] (64 AGPR), ring-2 x 24KB LDS -> 48KB total -> 2 blocks/CU.
// Per step: vmcnt(0) -> barrier -> stage(s+1) -> 8 ds_read_b128 ->
// setprio(1) 16 MFMA setprio(0). One barrier/step; cross-block TLP hides the
// drain (m97 mechanism). LDS buffer: A 16 chunks @0, B 8 chunks @8192 ushorts;
// buffer stride 12288 ushorts. Waves 0-3 stage 4 A-chunks; 4-7 stage 2 B.
// ---------------------------------------------------------------------------
#define STAGE2(t)                                                             \
  {                                                                           \
    ushort_t* ld_ = smem + ((t) & 1) * 12288 + slotu;                         \
    for (int q_ = 0; q_ < nst; ++q_)                                          \
      gll16(SRC + (((size_t)(cb[q_] + (t))) << 9) + lane8, ld_ + q_ * 512);   \
  }

#define GSTEPX(s, NSV)                                                        \
  {                                                                           \
    asm volatile("s_waitcnt vmcnt(0)" ::: "memory");                          \
    __builtin_amdgcn_s_barrier();                                             \
    if ((s) + 1 < (NSV)) STAGE2((s) + 1)                                      \
    const ushort_t* buf_ = smem + ((s) & 1) * 12288;                          \
    short8 af[4], bf[4];                                                      \
    _Pragma("unroll") for (int i_ = 0; i_ < 4; ++i_)                          \
        af[i_] = *(const short8*)(buf_ + (wm * 4 + i_) * 512 + lane8);        \
    _Pragma("unroll") for (int j_ = 0; j_ < 4; ++j_)                          \
        bf[j_] = *(const short8*)(buf_ + 8192 + (wn * 4 + j_) * 512 + lane8); \
    __builtin_amdgcn_s_setprio(1);                                            \
    _Pragma("unroll") for (int i_ = 0; i_ < 4; ++i_)                          \
      _Pragma("unroll") for (int j_ = 0; j_ < 4; ++j_)                        \
        acc[i_][j_] = __builtin_amdgcn_mfma_f32_16x16x32_bf16(                \
            af[i_], bf[j_], acc[i_][j_], 0, 0, 0);                            \
    __builtin_amdgcn_s_setprio(0);                                            \
  }

#define GEMM_PIPEX(NSV)                                                       \
  STAGE2(0)                                                                   \
  _Pragma("unroll 2") for (int s_ = 0; s_ < (NSV); ++s_) { GSTEPX(s_, (NSV)) }

// ---------------------------------------------------------------------------
// Layer-1 GEMM (per-head, 256x128 tile): h2 = ELU(z_h@W1_h^T + b1).
// Grid 1536 (512 thr): head = id&7 (pins head per XCD), j=id>>3: n_t=j%6,
// m_t=j/6. NS = 24. Epilogue: 64-row quarter LDS-transposes (pitch 136)
// -> h2b_sw fragment-tiled.
// ---------------------------------------------------------------------------
__global__ __launch_bounds__(512, 4) void gemm_l1_kernel(
    const ushort_t* __restrict__ Asw, const ushort_t* __restrict__ Bsw,
    const float* __restrict__ biasb, ushort_t* __restrict__ Csw) {
  __shared__ ushort_t smem[24576];     // 48 KB ring-2 (epilogue aliases)
  const int id = blockIdx.x;
  const int head = id & 7;
  const int j_id = id >> 3;
  const int n_t = j_id % 6;
  const int m_t = j_id / 6;            // 0..31
  const int tid = threadIdx.x;
  const int lane = tid & 63;
  const int w = tid >> 6;              // 0..7
  const int wm = w >> 1, wn = w & 1;   // wave tile: 64 x 64
  const int lrow = lane & 15, lq = lane >> 4;
  const int lane8 = lane * 8;
  const int nst = (w < 4) ? 4 : 2;
  const int slotu = (w < 4) ? w * 2048 : 8192 + (w - 4) * 1024;
  const ushort_t* SRC = (w < 4) ? Asw : Bsw;

  int cb[4];
#pragma unroll
  for (int q = 0; q < 4; ++q) {
    int v;
    if (w < 4)   // A = z_sw: rowblock*192 + head*24, +s per step
      v = (m_t * 16 + 4 * w + q) * 192 + head * 24;
    else         // B = w1t_sw: rowblock*24, +s per step (2 chunks used)
      v = (head * 48 + n_t * 8 + 2 * (w - 4) + (q & 1)) * 24;
    cb[q] = __builtin_amdgcn_readfirstlane(v);
  }

  floatx4 acc[4][4];
#pragma unroll
  for (int i = 0; i < 4; ++i)
#pragma unroll
    for (int j = 0; j < 4; ++j) acc[i][j] = {0.f, 0.f, 0.f, 0.f};

  GEMM_PIPEX(24)

  // epilogue: bias+ELU -> 64-row quarter LDS transpose -> fragment-tiled write
  __syncthreads();
  ushort_t* tile = smem;               // 64 x 136 ushorts (17.4 KB)
  const float* bias = biasb + head * 768 + n_t * 128;
#pragma unroll
  for (int q4 = 0; q4 < 4; ++q4) {
    if (q4) __syncthreads();
    if (wm == q4) {
#pragma unroll
      for (int i = 0; i < 4; ++i)
#pragma unroll
        for (int j = 0; j < 4; ++j) {
          int col = wn * 64 + j * 16 + lrow;
          float bv = bias[col];
#pragma unroll
          for (int r = 0; r < 4; ++r) {
            float v = acc[i][j][r] + bv;
            v = v > 0.f ? v : __expf(v) - 1.0f;  // ELU (fast exp)
            tile[(i * 16 + lq * 4 + r) * 136 + col] = f2bf(v);
          }
        }
    }
    __syncthreads();
#pragma unroll
    for (int cc = 0; cc < 2; ++cc) {
      int ch = w * 2 + cc;             // 16 chunks in the 64x128 quarter
      int RB = ch >> 2, kg = ch & 3;
      short8 vv =
          *(const short8*)&tile[(RB * 16 + lrow) * 136 + kg * 32 + lq * 8];
      size_t chunk_g = (size_t)(m_t * 16 + q4 * 4 + RB) * 192 + head * 24 +
                       n_t * 4 + kg;
      *((short8*)Csw + chunk_g * 64 + lane) = vv;
    }
  }
}

// ---------------------------------------------------------------------------
// Layer-2 GEMM split-K=4 (256x128 tile): partials fp32 row-major.
// Grid 768 (512 thr): c=id&7: sl=c>>1, mlo=c&1; j=id>>3: n_t=j%6,
// m_t=(j/6)*2+mlo. NS = 1536/32 = 48 steps.
// ---------------------------------------------------------------------------
__global__ __launch_bounds__(512, 4) void gemm_l2_kernel(
    const ushort_t* __restrict__ Asw, const ushort_t* __restrict__ Bsw,
    float* __restrict__ Cp) {
  __shared__ ushort_t smem[24576];     // 48 KB ring-2
  const int id = blockIdx.x;
  const int c = id & 7;
  const int sl = c >> 1;
  const int j_id = id >> 3;
  const int n_t = j_id % 6;
  const int m_t = (j_id / 6) * 2 + (c & 1);   // 0..31
  const int tid = threadIdx.x;
  const int lane = tid & 63;
  const int w = tid >> 6;
  const int wm = w >> 1, wn = w & 1;
  const int lrow = lane & 15, lq = lane >> 4;
  const int lane8 = lane * 8;
  const int nst = (w < 4) ? 4 : 2;
  const int slotu = (w < 4) ? w * 2048 : 8192 + (w - 4) * 1024;
  const ushort_t* SRC = (w < 4) ? Asw : Bsw;

  int cb[4];
#pragma unroll
  for (int q = 0; q < 4; ++q) {
    int v;
    if (w < 4)   // A = h2b_sw: rowblock*192 + sl*48, +s per step
      v = (m_t * 16 + 4 * w + q) * 192 + sl * 48;
    else         // B = w2t_sw: rowblock*192 + sl*48 (2 chunks used)
      v = (n_t * 8 + 2 * (w - 4) + (q & 1)) * 192 + sl * 48;
    cb[q] = __builtin_amdgcn_readfirstlane(v);
  }

  floatx4 acc[4][4];
#pragma unroll
  for (int i = 0; i < 4; ++i)
#pragma unroll
    for (int j = 0; j < 4; ++j) acc[i][j] = {0.f, 0.f, 0.f, 0.f};

  GEMM_PIPEX(48)

  float* C = Cp + (size_t)sl * N_NODES * 768;
  const int m0 = m_t * 256, n0 = n_t * 128;
#pragma unroll
  for (int i = 0; i < 4; ++i) {
    int row_b = m0 + wm * 64 + i * 16 + lq * 4;
#pragma unroll
    for (int j = 0; j < 4; ++j) {
      int col = n0 + wn * 64 + j * 16 + lrow;
#pragma unroll
      for (int r = 0; r < 4; ++r)
        C[(size_t)(row_b + r) * 768 + col] = acc[i][j][r];
    }
  }
}

// ---------------------------------------------------------------------------
// Fused: yb = bf16(sum of 4 partials); as2/ad2 = y . aS2/aD2 per node.
// 192 threads; float4 partial reads, short4 bf16 stores.
// ---------------------------------------------------------------------------
__global__ __launch_bounds__(192) void reduce_alpha2_kernel(
    const float* __restrict__ parts, const float* __restrict__ aS,
    const float* __restrict__ aD, ushort_t* __restrict__ yb,
    float* __restrict__ as2, float* __restrict__ ad2) {
  const int n = blockIdx.x;
  const int t = threadIdx.x;           // 0..191, cols 4t..4t+3
  const size_t S = (size_t)N_NODES * 768;
  const size_t base = (size_t)n * 768 + t * 4;
  float4 v0 = *(const float4*)(parts + base);
  float4 v1 = *(const float4*)(parts + base + S);
  float4 v2 = *(const float4*)(parts + base + 2 * S);
  float4 v3 = *(const float4*)(parts + base + 3 * S);
  float vx = v0.x + v1.x + v2.x + v3.x;
  float vy = v0.y + v1.y + v2.y + v3.y;
  float vz = v0.z + v1.z + v2.z + v3.z;
  float vw = v0.w + v1.w + v2.w + v3.w;
  short4v pb = {(short)f2bf(vx), (short)f2bf(vy), (short)f2bf(vz),
                (short)f2bf(vw)};
  *(short4v*)(yb + base) = pb;
  const float4 a4 = *(const float4*)(aS + t * 4);
  const float4 d4 = *(const float4*)(aD + t * 4);
  float ps = vx * a4.x + vy * a4.y + vz * a4.z + vw * a4.w;
  float pd = vx * d4.x + vy * d4.y + vz * d4.z + vw * d4.w;
  for (int off = 32; off > 0; off >>= 1) {
    ps += __shfl_down(ps, off, 64);
    pd += __shfl_down(pd, off, 64);
  }
  __shared__ float red[2][3];
  int w = t >> 6;
  if ((t & 63) == 0) { red[0][w] = ps; red[1][w] = pd; }
  __syncthreads();
  if (t == 0) as2[n] = red[0][0] + red[0][1] + red[0][2];
  if (t == 64) ad2[n] = red[1][0] + red[1][1] + red[1][2];
}

// ---------------------------------------------------------------------------
// Fused layer-2 attention (H=1) + bias: 384 threads, thread t owns cols
// 2t,2t+1 — one uint (2xbf16) load per edge row, float2 out store.
// ---------------------------------------------------------------------------
__global__ __launch_bounds__(384) void attn2_kernel(
    const ushort_t* __restrict__ yb, const float* __restrict__ as2,
    const float* __restrict__ ad2, const int* __restrict__ start,
    const int* __restrict__ deg, const int* __restrict__ csr,
    const int* __restrict__ src, const float* __restrict__ b2,
    float* __restrict__ out) {
  const int n = blockIdx.x;
  const int t = threadIdx.x;
  const int st = start[n], dg = deg[n];
  __shared__ float alphaS[64];
  __shared__ int sidx[64];
  __shared__ float red[6];
  __shared__ float invd_sh;

  const float adv = ad2[n];
  float pden = 0.f;
  for (int ei = t; ei < dg; ei += 384) {
    int e = csr[st + ei];
    int s = (e < N_EDGES) ? src[e] : (e - N_EDGES);
    float l = as2[s] + adv;
    l = l > 0.f ? l : 0.2f * l;
    pden += __expf(l);
  }
  for (int off = 32; off > 0; off >>= 1) pden += __shfl_down(pden, off, 64);
  if ((t & 63) == 0) red[t >> 6] = pden;
  __syncthreads();
  if (t == 0)
    invd_sh = 1.0f /
              (red[0] + red[1] + red[2] + red[3] + red[4] + red[5]);
  __syncthreads();
  const float invd = invd_sh;

  float a0 = 0.f, a1 = 0.f;
  for (int base = 0; base < dg; base += 64) {
    int cnt = dg - base; if (cnt > 64) cnt = 64;
    if (t < cnt) {
      int e = csr[st + base + t];
      int s = (e < N_EDGES) ? src[e] : (e - N_EDGES);
      float l = as2[s] + adv;
      l = l > 0.f ? l : 0.2f * l;
      alphaS[t] = __expf(l) * invd;
      sidx[t] = s;
    }
    __syncthreads();
    for (int ei = 0; ei < cnt; ++ei) {
      float al = alphaS[ei];
      unsigned u = *(const unsigned*)(yb + (size_t)sidx[ei] * 768 + 2 * t);
      a0 += al * __uint_as_float(u << 16);
      a1 += al * __uint_as_float(u & 0xffff0000u);
    }
    __syncthreads();
  }
  const float2 b = *(const float2*)(b2 + 2 * t);
  float2 o;
  o.x = a0 + b.x;
  o.y = a1 + b.y;
  *(float2*)(out + (size_t)n * 768 + 2 * t) = o;
}

// ---------------------------------------------------------------------------
extern "C" void kernel_launch(void* const* d_in, const int* in_sizes, int n_in,
                              void* d_out, int out_size, void* d_ws, size_t ws_size,
                              hipStream_t stream) {
  const float* x      = (const float*)d_in[0];
  const int*   ei     = (const int*)d_in[1];
  const float* W1     = (const float*)d_in[2];
  const float* a_src1 = (const float*)d_in[3];
  const float* a_dst1 = (const float*)d_in[4];
  const float* b1     = (const float*)d_in[5];
  const float* W2     = (const float*)d_in[6];
  const float* a_src2 = (const float*)d_in[7];
  const float* a_dst2 = (const float*)d_in[8];
  const float* b2     = (const float*)d_in[9];
  float* out = (float*)d_out;
  const int* src = ei;
  const int* dst = ei + N_EDGES;

  char* ws = (char*)d_ws;
  size_t off = 0;
  auto alloc = [&](size_t bytes) -> void* {
    void* p = ws + off;
    off = (off + bytes + 255) & ~(size_t)255;
    return p;
  };

  int* deg = (int*)alloc(N_NODES * 4);  // needs zero-init
  float* awS = (float*)alloc(768 * H1 * 4);  // needs zero-init (atomics)
  float* awD = (float*)alloc(768 * H1 * 4);  // needs zero-init (atomics)
  float* as1 = (float*)alloc(N_NODES * H1 * 4);
  float* ad1 = (float*)alloc(N_NODES * H1 * 4);
  float* as2 = (float*)alloc(N_NODES * 4);
  float* ad2 = (float*)alloc(N_NODES * 4);
  int* start  = (int*)alloc(N_NODES * 4);
  int* cursor = (int*)alloc(N_NODES * 4);
  int* csr    = (int*)alloc(E_TOT * 4);
  // +8192-byte pads kept (pipe reads exactly in-bounds, pads harmless)
  ushort_t* xb     = (ushort_t*)alloc((size_t)N_NODES * D_IN * 2);  // -> yb
  ushort_t* w1t_sw = (ushort_t*)alloc((size_t)HC1 * D_IN * 2 + 8192);
  ushort_t* w2t_sw = (ushort_t*)alloc((size_t)HC1 * D_IN * 2 + 8192);
  ushort_t* z_sw   = (ushort_t*)alloc((size_t)N_NODES * HC1 * 2 + 8192);
  ushort_t* h2b_sw = (ushort_t*)alloc((size_t)N_NODES * HC1 * 2 + 8192);
  ushort_t* yb  = xb;            // xb dead after attn1
  float* parts  = (float*)z_sw;  // z dead after gemm_l1 (96 MB <= 100.7 MB)
  (void)ws_size; (void)n_in; (void)in_sizes; (void)out_size;

  hipMemsetAsync(deg, 0, N_NODES * 4, stream);
  hipMemsetAsync(awS, 0, 768 * H1 * 4, stream);
  hipMemsetAsync(awD, 0, 768 * H1 * 4, stream);

  // weight prep: fused W1 transpose + aw dots; plain W2 transpose
  frag_transpose_aw_kernel<<<dim3(HC1 / 64, D_IN / 64), 256, 0, stream>>>(
      W1, w1t_sw, a_src1, a_dst1, awS, awD);
  frag_transpose_kernel<<<dim3(D_IN / 64, HC1 / 64), 256, 0, stream>>>(
      W2, w2t_sw, HC1, D_IN);
  node_prep_kernel<<<N_NODES, 256, 0, stream>>>(x, awS, awD, xb, as1, ad1);

  // CSR build (graph identical for both layers)
  deg_kernel<<<(E_TOT + 255) / 256, 256, 0, stream>>>(dst, deg);
  scan_kernel<<<1, 1024, 0, stream>>>(deg, start, cursor);
  fill_kernel<<<(E_TOT + 255) / 256, 256, 0, stream>>>(dst, cursor, csr);

  // layer-1: fused attention -> z_sw, then per-head 2-block/CU GEMM
  attn1_kernel<<<N_NODES, 256, 0, stream>>>(xb, as1, ad1, start, deg, csr,
                                            src, z_sw);
  gemm_l1_kernel<<<8 * 32 * 6, 512, 0, stream>>>(z_sw, w1t_sw, b1, h2b_sw);

  // layer-2: split-K GEMM -> fused reduce+alpha -> attn + bias
  gemm_l2_kernel<<<KSPLIT * 2 * 16 * 6, 512, 0, stream>>>(h2b_sw, w2t_sw,
                                                          parts);
  reduce_alpha2_kernel<<<N_NODES, 192, 0, stream>>>(parts, a_src2, a_dst2, yb,
                                                    as2, ad2);
  attn2_kernel<<<N_NODES, 384, 0, stream>>>(yb, as2, ad2, start, deg, csr,
                                            src, b2, out);
}

// Round 9
// 462.096 us; speedup vs baseline: 1.0553x; 1.0553x over previous
//
#include <hip/hip_runtime.h>
#include <hip/hip_bf16.h>

// ---------------------------------------------------------------------------
// GAT 2-layer model on MI355X — round 17 (consolidation).
// R16 post-mortem: doubling occupancy (21->35%) made gemm_l1 WORSE (108 µs,
// MfmaUtil 31%) -> the ~33% MFMA wall is invariant to schedule (5 variants),
// occupancy, tile, BK. GEMM lane closed at ~770 TF for these shapes.
// Noise band identified as ±15 µs (R10=462.4, R13=462.6 vs R11=479.7,
// R15=477.1 with overlapping components).
// R17 = exact best-measured config (R13): ring-4 BK=32 split-phase GEMMs,
// LDS-broadcast attn1, original 256-thr tails; plus two strictly-work-
// reducing changes verified in R16: prep_aw fused into W1 frag-transpose
// (kills a 19MB read pass + launch) and LDS-coalesced W2 frag-transpose.
// Layer1 commuted: z = softmax-agg of x rows; h2 = ELU(z_h @ W1_h + b1).
// Layer2: y = h2@W2 split-K=4 -> fused reduce+alpha -> attn2+b2.
// ---------------------------------------------------------------------------

#define N_NODES 8192
#define N_EDGES 32768
#define E_TOT   (N_EDGES + N_NODES)   // self-loops appended
#define D_IN    768
#define H1      8
#define HC1     (H1 * D_IN)           // 6144
#define KSPLIT  4
#define KSLICE  (HC1 / KSPLIT)        // 1536

typedef unsigned short ushort_t;
using short8  = __attribute__((ext_vector_type(8))) short;
using floatx4 = __attribute__((ext_vector_type(4))) float;

__device__ __forceinline__ float bf2f(unsigned short u) {
  return __uint_as_float(((unsigned)u) << 16);
}
__device__ __forceinline__ unsigned short f2bf(float f) {
  unsigned u = __float_as_uint(f);
  unsigned r = (u + 0x7fffu + ((u >> 16) & 1u)) >> 16;  // RNE
  return (unsigned short)r;
}

// async global->LDS: 16B per lane, wave-uniform LDS base (+lane*16 implicit),
// per-lane global src address.
__device__ __forceinline__ void gll16(const ushort_t* g, ushort_t* l) {
  __builtin_amdgcn_global_load_lds(
      (const __attribute__((address_space(1))) void*)g,
      (__attribute__((address_space(3))) void*)l, 16, 0, 0);
}

// ---------------------------------------------------------------------------
// frag_transpose (generic, W2): W[Kdim][Ndim] fp32 -> sw-layout Bt[N][K] bf16.
// 64x64 tile via padded LDS; coalesced 256-B row reads.
// ---------------------------------------------------------------------------
__global__ __launch_bounds__(256) void frag_transpose_kernel(
    const float* __restrict__ W, ushort_t* __restrict__ out,
    int Kdim, int Ndim) {
  __shared__ float lds[64 * 65];
  const int bx = blockIdx.x;           // n-tile (64 cols)
  const int by = blockIdx.y;           // k-tile (64 rows)
  const int tid = threadIdx.x;
  const int n0 = bx * 64, k0 = by * 64;
  const int nn = tid & 63, kq = tid >> 6;   // 4 rows per iter
#pragma unroll
  for (int it = 0; it < 16; ++it) {
    int kk = it * 4 + kq;
    lds[kk * 65 + nn] = W[(size_t)(k0 + kk) * Ndim + n0 + nn];
  }
  __syncthreads();
  const int Ksub = Kdim >> 5;
#pragma unroll
  for (int it = 0; it < 2; ++it) {
    int idx = tid + 256 * it;          // 0..511: 8 chunks x 64 lanes
    int c = idx >> 6, l = idx & 63;
    int cn = c >> 1, ck = c & 1;
    int lrow = l & 15, lq = l >> 4;
    int n_loc = cn * 16 + lrow;
    int kb = ck * 32 + lq * 8;
    ushort_t v[8];
#pragma unroll
    for (int e = 0; e < 8; ++e) v[e] = f2bf(lds[(kb + e) * 65 + n_loc]);
    size_t chunk = (size_t)(bx * 4 + cn) * Ksub + (by * 2 + ck);
    *(short8*)(out + chunk * 512 + l * 8) = *(short8*)v;
  }
}

// ---------------------------------------------------------------------------
// fused W1 transpose + aw dots: transpose (Kdim=768, Ndim=6144) PLUS
// per-tile partial awS/awD dots accumulated via atomics (awS/awD zeroed).
// awS[d*H1+h] = sum_c W1[d][h*768+c]*aS[h*768+c].
// ---------------------------------------------------------------------------
__global__ __launch_bounds__(256) void frag_transpose_aw_kernel(
    const float* __restrict__ W, ushort_t* __restrict__ out,
    const float* __restrict__ aS, const float* __restrict__ aD,
    float* __restrict__ awS, float* __restrict__ awD) {
  __shared__ float lds[64 * 65];
  const int bx = blockIdx.x;           // n-tile (64 of 6144)
  const int by = blockIdx.y;           // k-tile (64 of 768)
  const int tid = threadIdx.x;
  const int n0 = bx * 64, k0 = by * 64;
  const int nn = tid & 63, kq = tid >> 6;
#pragma unroll
  for (int it = 0; it < 16; ++it) {
    int kk = it * 4 + kq;
    lds[kk * 65 + nn] = W[(size_t)(k0 + kk) * 6144 + n0 + nn];
  }
  __syncthreads();
  // transpose output (Ksub = 24)
#pragma unroll
  for (int it = 0; it < 2; ++it) {
    int idx = tid + 256 * it;
    int c = idx >> 6, l = idx & 63;
    int cn = c >> 1, ck = c & 1;
    int lrow = l & 15, lq = l >> 4;
    int n_loc = cn * 16 + lrow;
    int kb = ck * 32 + lq * 8;
    ushort_t v[8];
#pragma unroll
    for (int e = 0; e < 8; ++e) v[e] = f2bf(lds[(kb + e) * 65 + n_loc]);
    size_t chunk = (size_t)(bx * 4 + cn) * 24 + (by * 2 + ck);
    *(short8*)(out + chunk * 512 + l * 8) = *(short8*)v;
  }
  // aw partial dots: row r = tid>>2, col quarter nq = tid&3
  const int r = tid >> 2, nq = tid & 3;
  float s_ = 0.f, d_ = 0.f;
  const float* aSp = aS + n0 + nq * 16;
  const float* aDp = aD + n0 + nq * 16;
#pragma unroll
  for (int c = 0; c < 16; ++c) {
    float v = lds[r * 65 + nq * 16 + c];
    s_ += v * aSp[c];
    d_ += v * aDp[c];
  }
  s_ += __shfl_down(s_, 2, 4); s_ += __shfl_down(s_, 1, 4);
  d_ += __shfl_down(d_, 2, 4); d_ += __shfl_down(d_, 1, 4);
  if (nq == 0) {
    int h = n0 / 768;
    atomicAdd(&awS[(k0 + r) * H1 + h], s_);
    atomicAdd(&awD[(k0 + r) * H1 + h], d_);
  }
}

// ---------------------------------------------------------------------------
// per node: xb = bf16(x); as1[n,h] = x[n,:]@awS[:,h]; ad1 likewise.
// ---------------------------------------------------------------------------
__global__ void node_prep_kernel(const float* __restrict__ x,
                                 const float* __restrict__ awS,
                                 const float* __restrict__ awD,
                                 ushort_t* __restrict__ xb,
                                 float* __restrict__ as1,
                                 float* __restrict__ ad1) {
  const int n = blockIdx.x;
  const int t = threadIdx.x;
  float ps[H1], pd[H1];
#pragma unroll
  for (int h = 0; h < H1; ++h) { ps[h] = 0.f; pd[h] = 0.f; }
#pragma unroll
  for (int j = 0; j < 3; ++j) {
    int d = j * 256 + t;
    float xv = x[(size_t)n * 768 + d];
    xb[(size_t)n * 768 + d] = f2bf(xv);
    const float4* s4 = (const float4*)(awS + d * 8);
    const float4* d4 = (const float4*)(awD + d * 8);
    float4 a0 = s4[0], a1 = s4[1];
    float4 c0 = d4[0], c1 = d4[1];
    ps[0] += xv * a0.x; ps[1] += xv * a0.y; ps[2] += xv * a0.z; ps[3] += xv * a0.w;
    ps[4] += xv * a1.x; ps[5] += xv * a1.y; ps[6] += xv * a1.z; ps[7] += xv * a1.w;
    pd[0] += xv * c0.x; pd[1] += xv * c0.y; pd[2] += xv * c0.z; pd[3] += xv * c0.w;
    pd[4] += xv * c1.x; pd[5] += xv * c1.y; pd[6] += xv * c1.z; pd[7] += xv * c1.w;
  }
#pragma unroll
  for (int h = 0; h < H1; ++h)
    for (int off = 32; off > 0; off >>= 1) {
      ps[h] += __shfl_down(ps[h], off, 64);
      pd[h] += __shfl_down(pd[h], off, 64);
    }
  __shared__ float red[2][4][H1];
  int w = t >> 6;
  if ((t & 63) == 0) {
#pragma unroll
    for (int h = 0; h < H1; ++h) { red[0][w][h] = ps[h]; red[1][w][h] = pd[h]; }
  }
  __syncthreads();
  if (t < H1)
    as1[n * H1 + t] = red[0][0][t] + red[0][1][t] + red[0][2][t] + red[0][3][t];
  else if (t >= 64 && t < 64 + H1) {
    int h = t - 64;
    ad1[n * H1 + h] = red[1][0][h] + red[1][1][h] + red[1][2][h] + red[1][3][h];
  }
}

// ---------------------------------------------------------------------------
// CSR build: deg -> exclusive scan -> fill
// ---------------------------------------------------------------------------
__global__ void deg_kernel(const int* __restrict__ dst, int* __restrict__ deg) {
  int e = blockIdx.x * blockDim.x + threadIdx.x;
  if (e >= E_TOT) return;
  int d = (e < N_EDGES) ? dst[e] : (e - N_EDGES);
  atomicAdd(&deg[d], 1);
}

__global__ void scan_kernel(const int* __restrict__ deg, int* __restrict__ start,
                            int* __restrict__ cursor) {
  __shared__ int sums[1024];
  int t = threadIdx.x;
  int base = t * 8;
  int local[8];
  int s = 0;
#pragma unroll
  for (int i = 0; i < 8; ++i) { local[i] = s; s += deg[base + i]; }
  sums[t] = s;
  __syncthreads();
  for (int off = 1; off < 1024; off <<= 1) {
    int v = (t >= off) ? sums[t - off] : 0;
    __syncthreads();
    sums[t] += v;
    __syncthreads();
  }
  int excl = (t == 0) ? 0 : sums[t - 1];
#pragma unroll
  for (int i = 0; i < 8; ++i) {
    int st = excl + local[i];
    start[base + i] = st;
    cursor[base + i] = st;
  }
}

__global__ void fill_kernel(const int* __restrict__ dst, int* __restrict__ cursor,
                            int* __restrict__ csr) {
  int e = blockIdx.x * blockDim.x + threadIdx.x;
  if (e >= E_TOT) return;
  int d = (e < N_EDGES) ? dst[e] : (e - N_EDGES);
  int pos = atomicAdd(&cursor[d], 1);
  csr[pos] = e;
}

// ---------------------------------------------------------------------------
// Fused layer-1 attention -> z in sw (fragment-tiled) layout. (R13)
// 16-edge chunks; source rows staged once into LDS (24 KB, coalesced uint4);
// inner FMA loop reads LDS instead of 8x-redundant global gathers.
// ---------------------------------------------------------------------------
__global__ __launch_bounds__(256) void attn1_kernel(
    const ushort_t* __restrict__ xb, const float* __restrict__ as1,
    const float* __restrict__ ad1, const int* __restrict__ start,
    const int* __restrict__ deg, const int* __restrict__ csr,
    const int* __restrict__ src, ushort_t* __restrict__ z_sw) {
  const int n = blockIdx.x;
  const int t = threadIdx.x;
  const int st = start[n], dg = deg[n];
  const int h = t & 7, eloc = t >> 3;  // phase A: 32 edges x 8 heads
  __shared__ float invd[H1];
  __shared__ float alphaS[16][H1];
  __shared__ int sidx[16];
  __shared__ float red[4][H1];
  __shared__ uint4 xs[16 * 96];        // 24 KB: 16 rows x 768 bf16

  // Phase A: denominators (no max-subtraction; logits bounded)
  const float adv = ad1[n * H1 + h];
  float pden = 0.f;
  for (int base = 0; base < dg; base += 32) {
    int ei = base + eloc;
    if (ei < dg) {
      int e = csr[st + ei];
      int s = (e < N_EDGES) ? src[e] : (e - N_EDGES);
      float l = as1[s * H1 + h] + adv;
      l = l > 0.f ? l : 0.2f * l;
      pden += __expf(l);
    }
  }
  pden += __shfl_down(pden, 8, 64);
  pden += __shfl_down(pden, 16, 64);
  pden += __shfl_down(pden, 32, 64);
  if ((t & 63) < 8) red[t >> 6][h] = pden;
  __syncthreads();
  if (t < 8) invd[t] = 1.0f / (red[0][t] + red[1][t] + red[2][t] + red[3][t]);
  __syncthreads();

  // per-pass ownership
  int hp[3], ip[3];
#pragma unroll
  for (int p = 0; p < 3; ++p) {
    int c8 = p * 256 + t;
    hp[p] = c8 / 96;          // head
    ip[p] = c8 % 96;          // uint4 index within a row
  }
  float acc[3][8];
#pragma unroll
  for (int p = 0; p < 3; ++p)
#pragma unroll
    for (int e = 0; e < 8; ++e) acc[p][e] = 0.f;

  for (int base = 0; base < dg; base += 16) {
    int cnt = dg - base; if (cnt > 16) cnt = 16;
    // alpha + sidx for this chunk (threads t<128: 16 edges x 8 heads)
    if (t < 128 && eloc < cnt) {
      int e = csr[st + base + eloc];
      int s = (e < N_EDGES) ? src[e] : (e - N_EDGES);
      float l = as1[s * H1 + h] + adv;
      l = l > 0.f ? l : 0.2f * l;
      alphaS[eloc][h] = __expf(l) * invd[h];
      if (h == 0) sidx[eloc] = s;
    }
    __syncthreads();
    // stage rows into LDS: 6 coalesced uint4 per thread (rows < cnt only)
#pragma unroll
    for (int j = 0; j < 6; ++j) {
      int idx = t + 256 * j;           // 0..1535
      int row = idx / 96;
      if (row < cnt) {
        int col = idx - row * 96;
        xs[idx] = *(const uint4*)(xb + (size_t)sidx[row] * 768 + col * 8);
      }
    }
    __syncthreads();
    for (int ei = 0; ei < cnt; ++ei) {
      const uint4* xr = &xs[ei * 96];
#pragma unroll
      for (int p = 0; p < 3; ++p) {
        uint4 v = xr[ip[p]];
        float al = alphaS[ei][hp[p]];
        unsigned uu[4] = {v.x, v.y, v.z, v.w};
#pragma unroll
        for (int q = 0; q < 4; ++q) {
          acc[p][2 * q]     += al * __uint_as_float(uu[q] << 16);
          acc[p][2 * q + 1] += al * __uint_as_float(uu[q] & 0xffff0000u);
        }
      }
    }
    __syncthreads();
  }
  // write sw layout: k = (p*256+t)*8
#pragma unroll
  for (int p = 0; p < 3; ++p) {
    int c8 = p * 256 + t;
    int k = c8 * 8;
    size_t chunk = (size_t)(n >> 4) * 192 + (k >> 5);
    int word = ((k >> 3) & 3) * 16 + (n & 15);
    ushort_t v[8];
#pragma unroll
    for (int e = 0; e < 8; ++e) v[e] = f2bf(acc[p][e]);
    *(short8*)(z_sw + chunk * 512 + word * 8) = *(short8*)v;
  }
}

// ---------------------------------------------------------------------------
// Counted-vmcnt ring-pipelined MFMA GEMM with phase-split K-step (R11 sched,
// best measured). 256x256 tile, BK=32. Ring-4 x 32 KB LDS; wave w stages 4
// chunks/step (w<4: A, w>=4: B); stage-ahead-3. Two 16-MFMA phases per step
// with an alignment barrier; vmcnt counted (8 steady / 4,0 peel).
// ---------------------------------------------------------------------------
#define STAGE_RING(t)                                                          \
  {                                                                            \
    ushort_t* ld_ = smem + ((t) & 3) * 16384 + slot512;                        \
    _Pragma("unroll") for (int q_ = 0; q_ < 4; ++q_)                           \
        gll16(SRC + (((size_t)(cb[q_] + (t))) << 9) + lane8, ld_ + q_ * 512);  \
  }

#define GSTEP_BODY(s, VMSTR, NSV)                                             \
  {                                                                           \
    asm volatile("s_waitcnt vmcnt(" VMSTR ")" ::: "memory");                  \
    __builtin_amdgcn_s_barrier();                                             \
    const ushort_t* buf_ = smem + ((s) & 3) * 16384;                          \
    short8 af[8], bf[4];                                                      \
    _Pragma("unroll") for (int j_ = 0; j_ < 4; ++j_)                          \
        bf[j_] = *(const short8*)(buf_ + 8192 + (wn * 4 + j_) * 512 + lane8); \
    _Pragma("unroll") for (int i_ = 0; i_ < 4; ++i_)                          \
        af[i_] = *(const short8*)(buf_ + (wm * 8 + i_) * 512 + lane8);        \
    if ((s) + 3 < (NSV)) STAGE_RING((s) + 3)                                  \
    __builtin_amdgcn_s_setprio(1);                                            \
    _Pragma("unroll") for (int i_ = 0; i_ < 4; ++i_)                          \
        _Pragma("unroll") for (int j_ = 0; j_ < 4; ++j_)                      \
            acc[i_][j_] = __builtin_amdgcn_mfma_f32_16x16x32_bf16(            \
                af[i_], bf[j_], acc[i_][j_], 0, 0, 0);                        \
    __builtin_amdgcn_s_setprio(0);                                            \
    _Pragma("unroll") for (int i_ = 4; i_ < 8; ++i_)                          \
        af[i_] = *(const short8*)(buf_ + (wm * 8 + i_) * 512 + lane8);        \
    __builtin_amdgcn_s_barrier();                                             \
    __builtin_amdgcn_s_setprio(1);                                            \
    _Pragma("unroll") for (int i_ = 4; i_ < 8; ++i_)                          \
        _Pragma("unroll") for (int j_ = 0; j_ < 4; ++j_)                      \
            acc[i_][j_] = __builtin_amdgcn_mfma_f32_16x16x32_bf16(            \
                af[i_], bf[j_], acc[i_][j_], 0, 0, 0);                        \
    __builtin_amdgcn_s_setprio(0);                                            \
  }

#define GEMM_PIPE(NSV)                                                        \
  _Pragma("unroll") for (int p_ = 0; p_ < 3; ++p_) STAGE_RING(p_)             \
  _Pragma("unroll 2") for (int s_ = 0; s_ < (NSV)-2; ++s_) {                  \
    GSTEP_BODY(s_, "8", (NSV))                                                \
  }                                                                           \
  GSTEP_BODY((NSV)-2, "4", (NSV))                                             \
  GSTEP_BODY((NSV)-1, "0", (NSV))

// ---------------------------------------------------------------------------
// Layer-1 GEMM (per-head, 256x256 tile): h2 = ELU(z_h@W1_h^T + b1).
// Grid 768 (512 thr): head = id&7 (pins head per XCD), j=id>>3: n_t=j%3,
// m_t=j/3. NS = 768/32 = 24 steps. Epilogue: LDS-transpose per 128-row half
// through the idle ring LDS (pitch 280 ushort) -> h2b_sw fragment-tiled.
// ---------------------------------------------------------------------------
__global__ __launch_bounds__(512, 2) void gemm_l1_kernel(
    const ushort_t* __restrict__ Asw, const ushort_t* __restrict__ Bsw,
    const float* __restrict__ biasb, ushort_t* __restrict__ Csw) {
  __shared__ ushort_t smem[4 * 16384];   // 128 KB ring (epilogue aliases)
  const int id = blockIdx.x;
  const int head = id & 7;
  const int j_id = id >> 3;
  const int n_t = j_id % 3;
  const int m_t = j_id / 3;
  const int tid = threadIdx.x;
  const int lane = tid & 63;
  const int w = tid >> 6;               // 0..7
  const int wm = w >> 2, wn = w & 3;    // wave tile: 128 x 64
  const int lrow = lane & 15, lq = lane >> 4;
  const int lane8 = lane * 8;
  const int slot512 = w * 2048;         // staging slots 4w..4w+3
  const ushort_t* SRC = (w < 4) ? Asw : Bsw;

  int cb[4];
#pragma unroll
  for (int q = 0; q < 4; ++q) {
    int v;
    if (w < 4)   // A = z_sw: rowblock*192 + head*24, +s per step
      v = (m_t * 16 + 4 * w + q) * 192 + head * 24;
    else         // B = w1t_sw: rowblock*24, +s per step
      v = (head * 48 + n_t * 16 + 4 * (w - 4) + q) * 24;
    cb[q] = __builtin_amdgcn_readfirstlane(v);
  }

  floatx4 acc[8][4];
#pragma unroll
  for (int i = 0; i < 8; ++i)
#pragma unroll
    for (int j = 0; j < 4; ++j) acc[i][j] = {0.f, 0.f, 0.f, 0.f};

  GEMM_PIPE(24)

  // epilogue: bias+ELU -> LDS half-tile transpose -> fragment-tiled write.
  // sync first: ring LDS is about to be overwritten.
  __syncthreads();
  ushort_t* tile = smem;                 // 128 x 280 ushorts (70 KB)
  const float* bias = biasb + head * 768 + n_t * 256;
#pragma unroll
  for (int p = 0; p < 2; ++p) {
    if (p) __syncthreads();
    if (wm == p) {
#pragma unroll
      for (int i = 0; i < 8; ++i)
#pragma unroll
        for (int j = 0; j < 4; ++j) {
          int col = wn * 64 + j * 16 + lrow;
          float bv = bias[col];
#pragma unroll
          for (int r = 0; r < 4; ++r) {
            float v = acc[i][j][r] + bv;
            v = v > 0.f ? v : __expf(v) - 1.0f;  // ELU (fast exp)
            tile[(i * 16 + lq * 4 + r) * 280 + col] = f2bf(v);
          }
        }
    }
    __syncthreads();
#pragma unroll
    for (int cc = 0; cc < 8; ++cc) {
      int ch = w * 8 + cc;              // 64 chunks in the 128x256 half
      int RB = ch >> 3, kg = ch & 7;
      short8 vv =
          *(const short8*)&tile[(RB * 16 + lrow) * 280 + kg * 32 + lq * 8];
      size_t chunk_g = (size_t)(m_t * 16 + p * 8 + RB) * 192 + head * 24 +
                       n_t * 8 + kg;
      *((short8*)Csw + chunk_g * 64 + lane) = vv;
    }
  }
}

// ---------------------------------------------------------------------------
// Layer-2 GEMM split-K=4 (256x256 tile): partials fp32 row-major.
// Grid 384 (512 thr): c=id&7: sl=c>>1 (K-slice per XCD-pair),
// j=id>>3: n_t=j%3, m_t=(j/3)*2+(c&1). NS = 1536/32 = 48 steps.
// ---------------------------------------------------------------------------
__global__ __launch_bounds__(512, 2) void gemm_l2_kernel(
    const ushort_t* __restrict__ Asw, const ushort_t* __restrict__ Bsw,
    float* __restrict__ Cp) {
  __shared__ ushort_t smem[4 * 16384];   // 128 KB ring
  const int id = blockIdx.x;
  const int c = id & 7;
  const int sl = c >> 1;
  const int j_id = id >> 3;
  const int n_t = j_id % 3;
  const int m_t = (j_id / 3) * 2 + (c & 1);
  const int tid = threadIdx.x;
  const int lane = tid & 63;
  const int w = tid >> 6;
  const int wm = w >> 2, wn = w & 3;
  const int lrow = lane & 15, lq = lane >> 4;
  const int lane8 = lane * 8;
  const int slot512 = w * 2048;
  const ushort_t* SRC = (w < 4) ? Asw : Bsw;

  int cb[4];
#pragma unroll
  for (int q = 0; q < 4; ++q) {
    int v;
    if (w < 4)   // A = h2b_sw: rowblock*192 + sl*48, +s per step
      v = (m_t * 16 + 4 * w + q) * 192 + sl * 48;
    else         // B = w2t_sw: rowblock*192 + sl*48, +s per step
      v = (n_t * 16 + 4 * (w - 4) + q) * 192 + sl * 48;
    cb[q] = __builtin_amdgcn_readfirstlane(v);
  }

  floatx4 acc[8][4];
#pragma unroll
  for (int i = 0; i < 8; ++i)
#pragma unroll
    for (int j = 0; j < 4; ++j) acc[i][j] = {0.f, 0.f, 0.f, 0.f};

  GEMM_PIPE(48)

  float* C = Cp + (size_t)sl * N_NODES * 768;
  const int m0 = m_t * 256, n0 = n_t * 256;
#pragma unroll
  for (int i = 0; i < 8; ++i) {
    int row_b = m0 + wm * 128 + i * 16 + lq * 4;
#pragma unroll
    for (int j = 0; j < 4; ++j) {
      int col = n0 + wn * 64 + j * 16 + lrow;
#pragma unroll
      for (int r = 0; r < 4; ++r)
        C[(size_t)(row_b + r) * 768 + col] = acc[i][j][r];
    }
  }
}

// ---------------------------------------------------------------------------
// Fused: yb = bf16(sum of 4 partials); as2/ad2 = y . a_src2/a_dst2 per node.
// ---------------------------------------------------------------------------
__global__ void reduce_alpha2_kernel(const float* __restrict__ parts,
                                     const float* __restrict__ aS,
                                     const float* __restrict__ aD,
                                     ushort_t* __restrict__ yb,
                                     float* __restrict__ as2,
                                     float* __restrict__ ad2) {
  const int n = blockIdx.x;
  const int t = threadIdx.x;
  const size_t S = (size_t)N_NODES * 768;
  float ps = 0.f, pd = 0.f;
#pragma unroll
  for (int j = 0; j < 3; ++j) {
    int cidx = j * 256 + t;
    size_t base = (size_t)n * 768 + cidx;
    float v = parts[base] + parts[base + S] + parts[base + 2 * S] +
              parts[base + 3 * S];
    yb[base] = f2bf(v);
    ps += v * aS[cidx];
    pd += v * aD[cidx];
  }
  for (int off = 32; off > 0; off >>= 1) {
    ps += __shfl_down(ps, off, 64);
    pd += __shfl_down(pd, off, 64);
  }
  __shared__ float red[2][4];
  int w = t >> 6;
  if ((t & 63) == 0) { red[0][w] = ps; red[1][w] = pd; }
  __syncthreads();
  if (t == 0) as2[n] = red[0][0] + red[0][1] + red[0][2] + red[0][3];
  if (t == 64) ad2[n] = red[1][0] + red[1][1] + red[1][2] + red[1][3];
}

// ---------------------------------------------------------------------------
// Fused layer-2 attention (H=1) + bias: out[n,c] = sum alpha*y[src,c] + b2.
// ---------------------------------------------------------------------------
__global__ __launch_bounds__(256) void attn2_kernel(
    const ushort_t* __restrict__ yb, const float* __restrict__ as2,
    const float* __restrict__ ad2, const int* __restrict__ start,
    const int* __restrict__ deg, const int* __restrict__ csr,
    const int* __restrict__ src, const float* __restrict__ b2,
    float* __restrict__ out) {
  const int n = blockIdx.x;
  const int t = threadIdx.x;
  const int st = start[n], dg = deg[n];
  __shared__ float alphaS[64];
  __shared__ int sidx[64];
  __shared__ float red[4];
  __shared__ float invd_sh;

  const float adv = ad2[n];
  float pden = 0.f;
  for (int ei = t; ei < dg; ei += 256) {
    int e = csr[st + ei];
    int s = (e < N_EDGES) ? src[e] : (e - N_EDGES);
    float l = as2[s] + adv;
    l = l > 0.f ? l : 0.2f * l;
    pden += __expf(l);
  }
  for (int off = 32; off > 0; off >>= 1) pden += __shfl_down(pden, off, 64);
  if ((t & 63) == 0) red[t >> 6] = pden;
  __syncthreads();
  if (t == 0) invd_sh = 1.0f / (red[0] + red[1] + red[2] + red[3]);
  __syncthreads();
  const float invd = invd_sh;

  float a0 = 0.f, a1 = 0.f, a2 = 0.f;
  for (int base = 0; base < dg; base += 64) {
    int cnt = dg - base; if (cnt > 64) cnt = 64;
    if (t < cnt) {
      int e = csr[st + base + t];
      int s = (e < N_EDGES) ? src[e] : (e - N_EDGES);
      float l = as2[s] + adv;
      l = l > 0.f ? l : 0.2f * l;
      alphaS[t] = __expf(l) * invd;
      sidx[t] = s;
    }
    __syncthreads();
    for (int ei = 0; ei < cnt; ++ei) {
      float al = alphaS[ei];
      const ushort_t* row = yb + (size_t)sidx[ei] * 768;
      a0 += al * bf2f(row[t]);
      a1 += al * bf2f(row[t + 256]);
      a2 += al * bf2f(row[t + 512]);
    }
    __syncthreads();
  }
  out[(size_t)n * 768 + t]       = a0 + b2[t];
  out[(size_t)n * 768 + t + 256] = a1 + b2[t + 256];
  out[(size_t)n * 768 + t + 512] = a2 + b2[t + 512];
}

// ---------------------------------------------------------------------------
extern "C" void kernel_launch(void* const* d_in, const int* in_sizes, int n_in,
                              void* d_out, int out_size, void* d_ws, size_t ws_size,
                              hipStream_t stream) {
  const float* x      = (const float*)d_in[0];
  const int*   ei     = (const int*)d_in[1];
  const float* W1     = (const float*)d_in[2];
  const float* a_src1 = (const float*)d_in[3];
  const float* a_dst1 = (const float*)d_in[4];
  const float* b1     = (const float*)d_in[5];
  const float* W2     = (const float*)d_in[6];
  const float* a_src2 = (const float*)d_in[7];
  const float* a_dst2 = (const float*)d_in[8];
  const float* b2     = (const float*)d_in[9];
  float* out = (float*)d_out;
  const int* src = ei;
  const int* dst = ei + N_EDGES;

  char* ws = (char*)d_ws;
  size_t off = 0;
  auto alloc = [&](size_t bytes) -> void* {
    void* p = ws + off;
    off = (off + bytes + 255) & ~(size_t)255;
    return p;
  };

  int* deg = (int*)alloc(N_NODES * 4);       // needs zero-init
  float* awS = (float*)alloc(768 * H1 * 4);  // needs zero-init (atomics)
  float* awD = (float*)alloc(768 * H1 * 4);  // needs zero-init (atomics)
  float* as1 = (float*)alloc(N_NODES * H1 * 4);
  float* ad1 = (float*)alloc(N_NODES * H1 * 4);
  float* as2 = (float*)alloc(N_NODES * 4);
  float* ad2 = (float*)alloc(N_NODES * 4);
  int* start  = (int*)alloc(N_NODES * 4);
  int* cursor = (int*)alloc(N_NODES * 4);
  int* csr    = (int*)alloc(E_TOT * 4);
  // +8192-byte pads kept (pipe reads exactly in-bounds, pads harmless)
  ushort_t* xb     = (ushort_t*)alloc((size_t)N_NODES * D_IN * 2);  // -> yb
  ushort_t* w1t_sw = (ushort_t*)alloc((size_t)HC1 * D_IN * 2 + 8192);
  ushort_t* w2t_sw = (ushort_t*)alloc((size_t)HC1 * D_IN * 2 + 8192);
  ushort_t* z_sw   = (ushort_t*)alloc((size_t)N_NODES * HC1 * 2 + 8192);
  ushort_t* h2b_sw = (ushort_t*)alloc((size_t)N_NODES * HC1 * 2 + 8192);
  ushort_t* yb  = xb;            // xb dead after attn1
  float* parts  = (float*)z_sw;  // z dead after gemm_l1 (96 MB <= 100.7 MB)
  (void)ws_size; (void)n_in; (void)in_sizes; (void)out_size;

  hipMemsetAsync(deg, 0, N_NODES * 4, stream);
  hipMemsetAsync(awS, 0, 768 * H1 * 4, stream);
  hipMemsetAsync(awD, 0, 768 * H1 * 4, stream);

  // weight prep: fused W1 transpose + aw dots; plain W2 transpose
  frag_transpose_aw_kernel<<<dim3(HC1 / 64, D_IN / 64), 256, 0, stream>>>(
      W1, w1t_sw, a_src1, a_dst1, awS, awD);
  frag_transpose_kernel<<<dim3(D_IN / 64, HC1 / 64), 256, 0, stream>>>(
      W2, w2t_sw, HC1, D_IN);
  node_prep_kernel<<<N_NODES, 256, 0, stream>>>(x, awS, awD, xb, as1, ad1);

  // CSR build (graph identical for both layers)
  deg_kernel<<<(E_TOT + 255) / 256, 256, 0, stream>>>(dst, deg);
  scan_kernel<<<1, 1024, 0, stream>>>(deg, start, cursor);
  fill_kernel<<<(E_TOT + 255) / 256, 256, 0, stream>>>(dst, cursor, csr);

  // layer-1: fused attention -> z_sw, then per-head ring-pipelined GEMM
  attn1_kernel<<<N_NODES, 256, 0, stream>>>(xb, as1, ad1, start, deg, csr,
                                            src, z_sw);
  gemm_l1_kernel<<<8 * 32 * 3, 512, 0, stream>>>(z_sw, w1t_sw, b1, h2b_sw);

  // layer-2: split-K ring-pipelined GEMM -> fused reduce+alpha -> attn + bias
  gemm_l2_kernel<<<KSPLIT * 2 * 16 * 3, 512, 0, stream>>>(h2b_sw, w2t_sw,
                                                          parts);
  reduce_alpha2_kernel<<<N_NODES, 256, 0, stream>>>(parts, a_src2, a_dst2, yb,
                                                    as2, ad2);
  attn2_kernel<<<N_NODES, 256, 0, stream>>>(yb, as2, ad2, start, deg, csr,
                                            src, b2, out);
}